// Round 1
// baseline (121.050 us; speedup 1.0000x reference)
//
#include <hip/hip_runtime.h>

// Problem constants (from reference)
// X: (8, 2048, 256) fp32; W1: (64,8); b1: (64); W2: (2,64); b2: (2)
// patches: p = 0..510, l = 4p..4p+7
// out: (8, 511, 256, 2) fp32
#define B_DIM 8
#define L_DIM 2048
#define C_DIM 256
#define P_CNT 511
#define H_DIM 64

// thread = (b, channel-pair, tile of 4 patches)
// tiles per (b,c-pair): ceil(511/4) = 128
// threads = 8 * 128 * 128 = 131072 = 512 blocks * 256

__device__ __forceinline__ float fast_gelu(float x) {
    // gelu(x) ~= x * (1 - 1/(1 + exp(2u))), u = 0.7978845608*(x + 0.044715 x^3)
    // fold the 2: u2 = x * (1.5957691216 + 0.0713548162 x^2)
    float x2 = x * x;
    float u2 = x * __builtin_fmaf(x2, 0.0713548162f, 1.5957691216f);
    float e  = __expf(u2);            // v_exp_f32 (+1 mul)
    return x - __fdividef(x, e + 1.0f); // rcp-based fast division
}

__global__ __launch_bounds__(256) void offset_predictor_kernel(
    const float* __restrict__ X,
    const float* __restrict__ W1,
    const float* __restrict__ b1,
    const float* __restrict__ W2,
    const float* __restrict__ b2,
    float* __restrict__ out)
{
    __shared__ float sW1[H_DIM * 8];   // 512
    __shared__ float sB1[H_DIM];       // 64
    __shared__ float sW2[2 * H_DIM];   // 128
    __shared__ float sB2[2];

    const int tx = threadIdx.x;
    // cooperative weight staging (706 floats)
    for (int i = tx; i < H_DIM * 8; i += 256) sW1[i] = W1[i];
    if (tx < H_DIM)     sB1[tx] = b1[tx];
    if (tx < 2 * H_DIM) sW2[tx] = W2[tx];
    if (tx < 2)         sB2[tx] = b2[tx];
    __syncthreads();

    const int tid   = blockIdx.x * 256 + tx;
    const int cpair = tid & 127;          // consecutive threads -> consecutive channels (coalesced)
    const int ptile = (tid >> 7) & 127;
    const int b     = tid >> 14;
    const int c0    = cpair * 2;
    const int p0    = ptile * 4;

    // Load X window: l = 4*p0 .. 4*p0+19 (covers 4 overlapping patches)
    const float* xb = X + (size_t)b * (L_DIM * C_DIM) + c0;
    float2 xv[20];
#pragma unroll
    for (int j = 0; j < 20; ++j) {
        int l = 4 * p0 + j;
        if (l > L_DIM - 1) l = L_DIM - 1;   // tail tile: clamp (result discarded)
        xv[j] = *(const float2*)(xb + (size_t)l * C_DIM);
    }

    const float bo0 = sB2[0], bo1 = sB2[1];
    // acc[p] = (c0/o0, c0/o1, c1/o0, c1/o1) -> matches contiguous output layout
    float4 acc[4];
#pragma unroll
    for (int p = 0; p < 4; ++p) acc[p] = make_float4(bo0, bo1, bo0, bo1);

    for (int h = 0; h < H_DIM; ++h) {
        const float4 wa = *(const float4*)(sW1 + h * 8);
        const float4 wb = *(const float4*)(sW1 + h * 8 + 4);
        const float b1h = sB1[h];
        const float w2a = sW2[h];
        const float w2b = sW2[H_DIM + h];

#pragma unroll
        for (int p = 0; p < 4; ++p) {
            const int j0 = 4 * p;
            float t0 = b1h, t1 = b1h;
#define TAP(J, W) \
            t0 = __builtin_fmaf(xv[j0 + (J)].x, (W), t0); \
            t1 = __builtin_fmaf(xv[j0 + (J)].y, (W), t1);
            TAP(0, wa.x) TAP(1, wa.y) TAP(2, wa.z) TAP(3, wa.w)
            TAP(4, wb.x) TAP(5, wb.y) TAP(6, wb.z) TAP(7, wb.w)
#undef TAP
            const float g0 = fast_gelu(t0);
            const float g1 = fast_gelu(t1);
            acc[p].x = __builtin_fmaf(g0, w2a, acc[p].x);
            acc[p].y = __builtin_fmaf(g0, w2b, acc[p].y);
            acc[p].z = __builtin_fmaf(g1, w2a, acc[p].z);
            acc[p].w = __builtin_fmaf(g1, w2b, acc[p].w);
        }
    }

    // store: out[((b*511 + p)*256 + c)*2 + o]; (c0..c0+1, o0..o1) = contiguous float4
    float* ob = out + (size_t)b * (P_CNT * C_DIM * 2) + (size_t)c0 * 2;
#pragma unroll
    for (int p = 0; p < 4; ++p) {
        const int pp = p0 + p;
        if (pp < P_CNT) {
            *(float4*)(ob + (size_t)pp * (C_DIM * 2)) = acc[p];
        }
    }
}

extern "C" void kernel_launch(void* const* d_in, const int* in_sizes, int n_in,
                              void* d_out, int out_size, void* d_ws, size_t ws_size,
                              hipStream_t stream) {
    const float* X  = (const float*)d_in[0];
    const float* W1 = (const float*)d_in[1];
    const float* b1 = (const float*)d_in[2];
    const float* W2 = (const float*)d_in[3];
    const float* b2 = (const float*)d_in[4];
    float* out = (float*)d_out;

    // 131072 threads = 512 blocks x 256
    offset_predictor_kernel<<<512, 256, 0, stream>>>(X, W1, b1, W2, b2, out);
}

// Round 2
// 104.867 us; speedup vs baseline: 1.1543x; 1.1543x over previous
//
#include <hip/hip_runtime.h>

// X: (8, 2048, 256) fp32; W1: (64,8); b1: (64); W2: (2,64); b2: (2)
// patches: p = 0..510, l = 4p..4p+7 ; out: (8, 511, 256, 2) fp32
#define L_DIM 2048
#define C_DIM 256
#define P_CNT 511
#define H_DIM 64

// gelu(x) ~= x * sigmoid(2u), u = 0.7978845608*(x + 0.044715 x^3)
//          = x * rcp(1 + exp(x*(c1 + c2*x^2))),  c1=-1.5957691216, c2=-0.0713548162
__device__ __forceinline__ float fast_gelu(float x) {
    float x2 = x * x;
    float t  = x * __builtin_fmaf(x2, -0.0713548162f, -1.5957691216f);
    float e  = __expf(t);                       // v_mul + v_exp_f32
    return x * __builtin_amdgcn_rcpf(1.0f + e); // raw v_rcp_f32
}

// thread = (b, channel-pair, tile of 2 patches)
// threads = 8 * 128 * 256 = 262144 = 1024 blocks * 256
__global__ __launch_bounds__(256, 4) void offset_predictor_kernel(
    const float* __restrict__ X,
    const float* __restrict__ W1,
    const float* __restrict__ b1,
    const float* __restrict__ W2,
    const float* __restrict__ b2,
    float* __restrict__ out)
{
    // packed per-h weight row: [w1[0..7], b1[h], W2[0][h], W2[1][h], pad] (12 floats, 16B-aligned reads)
    __shared__ float sWp[H_DIM * 12];
    __shared__ float sB2[2];

    const int tx = threadIdx.x;
    if (tx < H_DIM) {
        float4 wa = *(const float4*)(W1 + tx * 8);
        float4 wb = *(const float4*)(W1 + tx * 8 + 4);
        *(float4*)(sWp + tx * 12)     = wa;
        *(float4*)(sWp + tx * 12 + 4) = wb;
        sWp[tx * 12 + 8]  = b1[tx];
        sWp[tx * 12 + 9]  = W2[tx];           // W2[0][h]
        sWp[tx * 12 + 10] = W2[H_DIM + tx];   // W2[1][h]
        sWp[tx * 12 + 11] = 0.0f;
    }
    if (tx < 2) sB2[tx] = b2[tx];
    __syncthreads();

    const int tid   = blockIdx.x * 256 + tx;
    const int cpair = tid & 127;            // consecutive threads -> consecutive channels (coalesced)
    const int ptile = (tid >> 7) & 255;
    const int b     = tid >> 15;
    const int c0    = cpair * 2;
    const int p0    = ptile * 2;

    // X window for 2 overlapping patches: l = 4*p0 .. 4*p0+11  (24 VGPRs — stays resident)
    const float* xb = X + (size_t)b * (L_DIM * C_DIM) + c0;
    float2 xv[12];
#pragma unroll
    for (int j = 0; j < 12; ++j) {
        int l = 4 * p0 + j;
        if (l > L_DIM - 1) l = L_DIM - 1;   // only ptile=255's second (invalid) patch hits this
        xv[j] = *(const float2*)(xb + (size_t)l * C_DIM);
    }

    const float bo0 = sB2[0], bo1 = sB2[1];
    // acc layout (c0/o0, c0/o1, c1/o0, c1/o1) == contiguous output float4
    float4 acc0 = make_float4(bo0, bo1, bo0, bo1);   // patch p0
    float4 acc1 = make_float4(bo0, bo1, bo0, bo1);   // patch p0+1

#pragma unroll 8
    for (int h = 0; h < H_DIM; ++h) {
        const float4 wa = *(const float4*)(sWp + h * 12);      // w1[0..3]
        const float4 wb = *(const float4*)(sWp + h * 12 + 4);  // w1[4..7]
        const float4 wc = *(const float4*)(sWp + h * 12 + 8);  // b1, w2o0, w2o1, pad

        float t0 = wc.x, t1 = wc.x;   // patch0: channels c0, c1
        float u0 = wc.x, u1 = wc.x;   // patch1
#define TAP(A0, A1, J, W) \
        A0 = __builtin_fmaf(xv[J].x, (W), A0); \
        A1 = __builtin_fmaf(xv[J].y, (W), A1);
        TAP(t0, t1, 0, wa.x) TAP(t0, t1, 1, wa.y) TAP(t0, t1, 2, wa.z) TAP(t0, t1, 3, wa.w)
        TAP(t0, t1, 4, wb.x) TAP(t0, t1, 5, wb.y) TAP(t0, t1, 6, wb.z) TAP(t0, t1, 7, wb.w)
        TAP(u0, u1, 4, wa.x) TAP(u0, u1, 5, wa.y) TAP(u0, u1, 6, wa.z) TAP(u0, u1, 7, wa.w)
        TAP(u0, u1, 8, wb.x) TAP(u0, u1, 9, wb.y) TAP(u0, u1, 10, wb.z) TAP(u0, u1, 11, wb.w)
#undef TAP
        const float g0 = fast_gelu(t0);
        const float g1 = fast_gelu(t1);
        const float g2 = fast_gelu(u0);
        const float g3 = fast_gelu(u1);
        acc0.x = __builtin_fmaf(g0, wc.y, acc0.x);
        acc0.y = __builtin_fmaf(g0, wc.z, acc0.y);
        acc0.z = __builtin_fmaf(g1, wc.y, acc0.z);
        acc0.w = __builtin_fmaf(g1, wc.z, acc0.w);
        acc1.x = __builtin_fmaf(g2, wc.y, acc1.x);
        acc1.y = __builtin_fmaf(g2, wc.z, acc1.y);
        acc1.z = __builtin_fmaf(g3, wc.y, acc1.z);
        acc1.w = __builtin_fmaf(g3, wc.z, acc1.w);
    }

    // out[((b*511 + p)*256 + c0)*2] : (c0,c0+1)x(o0,o1) = one contiguous float4
    float* ob = out + (size_t)b * (P_CNT * C_DIM * 2) + (size_t)c0 * 2;
    *(float4*)(ob + (size_t)p0 * (C_DIM * 2)) = acc0;           // p0 <= 510 always valid
    if (p0 + 1 < P_CNT)
        *(float4*)(ob + (size_t)(p0 + 1) * (C_DIM * 2)) = acc1;
}

extern "C" void kernel_launch(void* const* d_in, const int* in_sizes, int n_in,
                              void* d_out, int out_size, void* d_ws, size_t ws_size,
                              hipStream_t stream) {
    const float* X  = (const float*)d_in[0];
    const float* W1 = (const float*)d_in[1];
    const float* b1 = (const float*)d_in[2];
    const float* W2 = (const float*)d_in[3];
    const float* b2 = (const float*)d_in[4];
    float* out = (float*)d_out;

    offset_predictor_kernel<<<1024, 256, 0, stream>>>(X, W1, b1, W2, b2, out);
}

// Round 3
// 101.901 us; speedup vs baseline: 1.1879x; 1.0291x over previous
//
#include <hip/hip_runtime.h>

// X: (8, 2048, 256) fp32; W1: (64,8); b1: (64); W2: (2,64); b2: (2)
// patches: p = 0..510, l = 4p..4p+7 ; out: (8, 511, 256, 2) fp32
#define L_DIM 2048
#define C_DIM 256
#define P_CNT 511
#define H_DIM 64

// gelu(x) ~= x * sigmoid(2u), u = 0.7978845608*(x + 0.044715 x^3)
//          = x * rcp(1 + exp(x*(c1 + c2*x^2))),  c1=-1.5957691216, c2=-0.0713548162
__device__ __forceinline__ float fast_gelu(float x) {
    float x2 = x * x;
    float t  = x * __builtin_fmaf(x2, -0.0713548162f, -1.5957691216f);
    float e  = __expf(t);                       // v_mul + v_exp_f32
    return x * __builtin_amdgcn_rcpf(1.0f + e); // v_add + v_rcp_f32 + v_mul
}

// thread = (b, channel, tile of 2 patches)
// threads = 8 * 256 * 256 = 524288 = 2048 blocks * 256 -> 8 blocks/CU, 32 waves/CU
__global__ __launch_bounds__(256, 8) void offset_predictor_kernel(
    const float* __restrict__ X,
    const float* __restrict__ W1,
    const float* __restrict__ b1,
    const float* __restrict__ W2,
    const float* __restrict__ b2,
    float* __restrict__ out)
{
    const int tid   = blockIdx.x * 256 + threadIdx.x;
    const int c     = tid & 255;            // consecutive threads -> consecutive channels (coalesced)
    const int ptile = (tid >> 8) & 255;
    const int b     = tid >> 16;
    const int p0    = ptile * 2;

    // X window for 2 overlapping patches: l = 4*p0 .. 4*p0+11  (12 VGPRs)
    const float* xb = X + (size_t)b * (L_DIM * C_DIM) + c;
    float xv[12];
#pragma unroll
    for (int j = 0; j < 12; ++j) {
        int l = 4 * p0 + j;
        if (l > L_DIM - 1) l = L_DIM - 1;   // only ptile=255's invalid second patch hits this
        xv[j] = xb[(size_t)l * C_DIM];
    }

    // All weight reads below have wave-uniform addresses -> compiler emits s_load
    // (SGPR operands are free in v_fma; no LDS, no ds_read stalls).
    const float bo0 = b2[0], bo1 = b2[1];
    float2 acc0 = make_float2(bo0, bo1);    // patch p0   : (o0, o1)
    float2 acc1 = make_float2(bo0, bo1);    // patch p0+1

#pragma unroll 4
    for (int h = 0; h < H_DIM; ++h) {
        const float4 wa  = *(const float4*)(W1 + h * 8);      // w1[h][0..3]
        const float4 wb  = *(const float4*)(W1 + h * 8 + 4);  // w1[h][4..7]
        const float b1h  = b1[h];
        const float w2a  = W2[h];            // W2[0][h]
        const float w2b  = W2[H_DIM + h];    // W2[1][h]

        float t0 = b1h;   // patch0
        float u0 = b1h;   // patch1
        t0 = __builtin_fmaf(xv[0],  wa.x, t0);
        t0 = __builtin_fmaf(xv[1],  wa.y, t0);
        t0 = __builtin_fmaf(xv[2],  wa.z, t0);
        t0 = __builtin_fmaf(xv[3],  wa.w, t0);
        t0 = __builtin_fmaf(xv[4],  wb.x, t0);
        t0 = __builtin_fmaf(xv[5],  wb.y, t0);
        t0 = __builtin_fmaf(xv[6],  wb.z, t0);
        t0 = __builtin_fmaf(xv[7],  wb.w, t0);
        u0 = __builtin_fmaf(xv[4],  wa.x, u0);
        u0 = __builtin_fmaf(xv[5],  wa.y, u0);
        u0 = __builtin_fmaf(xv[6],  wa.z, u0);
        u0 = __builtin_fmaf(xv[7],  wa.w, u0);
        u0 = __builtin_fmaf(xv[8],  wb.x, u0);
        u0 = __builtin_fmaf(xv[9],  wb.y, u0);
        u0 = __builtin_fmaf(xv[10], wb.z, u0);
        u0 = __builtin_fmaf(xv[11], wb.w, u0);

        const float g0 = fast_gelu(t0);
        const float g1 = fast_gelu(u0);
        acc0.x = __builtin_fmaf(g0, w2a, acc0.x);
        acc0.y = __builtin_fmaf(g0, w2b, acc0.y);
        acc1.x = __builtin_fmaf(g1, w2a, acc1.x);
        acc1.y = __builtin_fmaf(g1, w2b, acc1.y);
    }

    // out[((b*511 + p)*256 + c)*2 + o] : (o0,o1) = one contiguous float2 per thread,
    // consecutive c -> contiguous 8B stores (512B/wave, coalesced)
    float* ob = out + ((size_t)(b * P_CNT) * C_DIM + c) * 2;
    *(float2*)(ob + (size_t)p0 * (C_DIM * 2)) = acc0;           // p0 <= 510 always valid
    if (p0 + 1 < P_CNT)
        *(float2*)(ob + (size_t)(p0 + 1) * (C_DIM * 2)) = acc1;
}

extern "C" void kernel_launch(void* const* d_in, const int* in_sizes, int n_in,
                              void* d_out, int out_size, void* d_ws, size_t ws_size,
                              hipStream_t stream) {
    const float* X  = (const float*)d_in[0];
    const float* W1 = (const float*)d_in[1];
    const float* b1 = (const float*)d_in[2];
    const float* W2 = (const float*)d_in[3];
    const float* b2 = (const float*)d_in[4];
    float* out = (float*)d_out;

    offset_predictor_kernel<<<2048, 256, 0, stream>>>(X, W1, b1, W2, b2, out);
}

// Round 4
// 100.997 us; speedup vs baseline: 1.1986x; 1.0090x over previous
//
#include <hip/hip_runtime.h>

// X: (8, 2048, 256) fp32; W1: (64,8); b1: (64); W2: (2,64); b2: (2)
// patches: p = 0..510, l = 4p..4p+7 ; out: (8, 511, 256, 2) fp32
#define L_DIM 2048
#define C_DIM 256
#define P_CNT 511
#define H_DIM 64

// gelu(x) ~= x * sigmoid(2u), u = 0.7978845608*(x + 0.044715 x^3)
// Express with exp2 (native v_exp_f32), folding log2(e) into the constants:
//   z = x*(k1 + k2*x^2), k1 = -1.5957691216*log2(e) = -2.3022038
//                        k2 = -0.0713548162*log2(e) = -0.10294324
//   gelu(x) = x * rcp(1 + 2^z)
// x->+inf: z->-inf, 2^z->0, g->x. x->-inf: 2^z->inf, rcp->0, g->0. (inf-safe)
__device__ __forceinline__ float fast_gelu(float x) {
    float x2 = x * x;
    float z  = x * __builtin_fmaf(x2, -0.10294324f, -2.3022038f);
    float e  = __builtin_amdgcn_exp2f(z);        // single v_exp_f32
    return x * __builtin_amdgcn_rcpf(1.0f + e);  // v_add + v_rcp_f32 + v_mul
}

// thread = (b, channel, tile of 2 patches)
// threads = 8 * 256 * 256 = 524288 = 2048 blocks * 256
__global__ __launch_bounds__(256, 8) void offset_predictor_kernel(
    const float* __restrict__ X,
    const float* __restrict__ W1,
    const float* __restrict__ b1,
    const float* __restrict__ W2,
    const float* __restrict__ b2,
    float* __restrict__ out)
{
    const int tid   = blockIdx.x * 256 + threadIdx.x;
    const int c     = tid & 255;            // consecutive threads -> consecutive channels (coalesced)
    const int ptile = (tid >> 8) & 255;
    const int b     = tid >> 16;
    const int p0    = ptile * 2;

    // X window for 2 overlapping patches: l = 4*p0 .. 4*p0+11  (12 VGPRs)
    const float* xb = X + (size_t)b * (L_DIM * C_DIM) + c;
    float xv[12];
#pragma unroll
    for (int j = 0; j < 12; ++j) {
        int l = 4 * p0 + j;
        if (l > L_DIM - 1) l = L_DIM - 1;   // only ptile=255's invalid second patch hits this
        xv[j] = xb[(size_t)l * C_DIM];
    }

    // Wave-uniform weight addresses -> s_load into SGPRs (free operands in v_fma).
    const float bo0 = b2[0], bo1 = b2[1];
    float2 acc0 = make_float2(bo0, bo1);    // patch p0   : (o0, o1)
    float2 acc1 = make_float2(bo0, bo1);    // patch p0+1

#pragma unroll 4
    for (int h = 0; h < H_DIM; ++h) {
        const float4 wa  = *(const float4*)(W1 + h * 8);      // w1[h][0..3]
        const float4 wb  = *(const float4*)(W1 + h * 8 + 4);  // w1[h][4..7]
        const float b1h  = b1[h];
        const float w2a  = W2[h];            // W2[0][h]
        const float w2b  = W2[H_DIM + h];    // W2[1][h]

        float t0 = b1h;   // patch0
        float u0 = b1h;   // patch1
        t0 = __builtin_fmaf(xv[0],  wa.x, t0);
        t0 = __builtin_fmaf(xv[1],  wa.y, t0);
        t0 = __builtin_fmaf(xv[2],  wa.z, t0);
        t0 = __builtin_fmaf(xv[3],  wa.w, t0);
        t0 = __builtin_fmaf(xv[4],  wb.x, t0);
        t0 = __builtin_fmaf(xv[5],  wb.y, t0);
        t0 = __builtin_fmaf(xv[6],  wb.z, t0);
        t0 = __builtin_fmaf(xv[7],  wb.w, t0);
        u0 = __builtin_fmaf(xv[4],  wa.x, u0);
        u0 = __builtin_fmaf(xv[5],  wa.y, u0);
        u0 = __builtin_fmaf(xv[6],  wa.z, u0);
        u0 = __builtin_fmaf(xv[7],  wa.w, u0);
        u0 = __builtin_fmaf(xv[8],  wb.x, u0);
        u0 = __builtin_fmaf(xv[9],  wb.y, u0);
        u0 = __builtin_fmaf(xv[10], wb.z, u0);
        u0 = __builtin_fmaf(xv[11], wb.w, u0);

        const float g0 = fast_gelu(t0);
        const float g1 = fast_gelu(u0);
        acc0.x = __builtin_fmaf(g0, w2a, acc0.x);
        acc0.y = __builtin_fmaf(g0, w2b, acc0.y);
        acc1.x = __builtin_fmaf(g1, w2a, acc1.x);
        acc1.y = __builtin_fmaf(g1, w2b, acc1.y);
    }

    // out[((b*511 + p)*256 + c)*2 + o] : contiguous float2 per thread, coalesced across c
    float* ob = out + ((size_t)(b * P_CNT) * C_DIM + c) * 2;
    *(float2*)(ob + (size_t)p0 * (C_DIM * 2)) = acc0;           // p0 <= 510 always valid
    if (p0 + 1 < P_CNT)
        *(float2*)(ob + (size_t)(p0 + 1) * (C_DIM * 2)) = acc1;
}

extern "C" void kernel_launch(void* const* d_in, const int* in_sizes, int n_in,
                              void* d_out, int out_size, void* d_ws, size_t ws_size,
                              hipStream_t stream) {
    const float* X  = (const float*)d_in[0];
    const float* W1 = (const float*)d_in[1];
    const float* b1 = (const float*)d_in[2];
    const float* W2 = (const float*)d_in[3];
    const float* b2 = (const float*)d_in[4];
    float* out = (float*)d_out;

    offset_predictor_kernel<<<2048, 256, 0, stream>>>(X, W1, b1, W2, b2, out);
}

// Round 6
// 98.079 us; speedup vs baseline: 1.2342x; 1.0297x over previous
//
#include <hip/hip_runtime.h>

// X: (8, 2048, 256) fp32; W1: (64,8); b1: (64); W2: (2,64); b2: (2)
// patches: p = 0..510, l = 4p..4p+7 ; out: (8, 511, 256, 2) fp32
#define L_DIM 2048
#define C_DIM 256
#define P_CNT 511
#define H_DIM 64

// Reference gelu (tanh-form via native exp2) — used ONLY to fill the LDS table.
// z = x*(k1 + k2*x^2), k1=-1.5957691216*log2e, k2=-0.0713548162*log2e
__device__ __forceinline__ float ref_gelu(float x) {
    float x2 = x * x;
    float z  = x * __builtin_fmaf(x2, -0.10294324f, -2.3022038f);
    float e  = __builtin_amdgcn_exp2f(z);
    return x * __builtin_amdgcn_rcpf(1.0f + e);
}

// Table gelu: 256 intervals over [-4,4), entry i = (v_i, v_{i+1}-v_i).
// ~10 cheap VALU ops + 1 ds_read_b64; zero transcendentals.
//  - t < -4: clamp to first knot -> gelu(-4) ~= -1.3e-4 (|err| <= 1.3e-4)
//  - t >  4: interpolant would return ~gelu(4); select t instead
//    (true gelu(t) = t - t*(1-Phi(t)), |err| < 1.3e-4). Select applies ONLY
//    for t > 4 — mid-range positive t keeps the interpolant (R4 bug fixed).
__device__ __forceinline__ float tgelu(float t, const float2* __restrict__ sT) {
    float f = __builtin_fmaf(t, 32.0f, 128.0f);
    f = fminf(fmaxf(f, 0.0f), 255.999f);
    int   i    = (int)f;              // f >= 0: trunc == floor
    float frac = f - (float)i;
    float2 e   = sT[i];               // ds_read_b64 (lgkm pipe)
    float g    = __builtin_fmaf(frac, e.y, e.x);
    return (t > 4.0f) ? t : g;        // v_cmp + v_cndmask
}

// thread = (b, channel, tile of 2 patches)
// threads = 8 * 256 * 256 = 524288 = 2048 blocks * 256
__global__ __launch_bounds__(256, 8) void offset_predictor_kernel(
    const float* __restrict__ X,
    const float* __restrict__ W1,
    const float* __restrict__ b1,
    const float* __restrict__ W2,
    const float* __restrict__ b2,
    float* __restrict__ out)
{
    __shared__ float2 sT[256];        // 2 KB gelu table (value, delta) per 1/32 interval

    const int tx = threadIdx.x;
    {   // one-time fill: all 256 threads, 2 exp-gelus each
        float xi = -4.0f + (float)tx * 0.03125f;
        float v0 = ref_gelu(xi);
        float v1 = ref_gelu(xi + 0.03125f);
        sT[tx] = make_float2(v0, v1 - v0);
    }
    __syncthreads();

    const int tid   = blockIdx.x * 256 + tx;
    const int c     = tid & 255;            // consecutive threads -> consecutive channels (coalesced)
    const int ptile = (tid >> 8) & 255;
    const int b     = tid >> 16;
    const int p0    = ptile * 2;

    // X window for 2 overlapping patches: l = 4*p0 .. 4*p0+11  (12 VGPRs)
    const float* xb = X + (size_t)b * (L_DIM * C_DIM) + c;
    float xv[12];
#pragma unroll
    for (int j = 0; j < 12; ++j) {
        int l = 4 * p0 + j;
        if (l > L_DIM - 1) l = L_DIM - 1;   // only ptile=255's invalid second patch hits this
        xv[j] = xb[(size_t)l * C_DIM];
    }

    // Wave-uniform weight addresses -> s_load into SGPRs (free operands in v_fma).
    const float bo0 = b2[0], bo1 = b2[1];
    float2 acc0 = make_float2(bo0, bo1);    // patch p0   : (o0, o1)
    float2 acc1 = make_float2(bo0, bo1);    // patch p0+1

#pragma unroll 4
    for (int h = 0; h < H_DIM; ++h) {
        const float4 wa  = *(const float4*)(W1 + h * 8);      // w1[h][0..3]
        const float4 wb  = *(const float4*)(W1 + h * 8 + 4);  // w1[h][4..7]
        const float b1h  = b1[h];
        const float w2a  = W2[h];            // W2[0][h]
        const float w2b  = W2[H_DIM + h];    // W2[1][h]

        float t0 = b1h;   // patch0
        float u0 = b1h;   // patch1
        t0 = __builtin_fmaf(xv[0],  wa.x, t0);
        t0 = __builtin_fmaf(xv[1],  wa.y, t0);
        t0 = __builtin_fmaf(xv[2],  wa.z, t0);
        t0 = __builtin_fmaf(xv[3],  wa.w, t0);
        t0 = __builtin_fmaf(xv[4],  wb.x, t0);
        t0 = __builtin_fmaf(xv[5],  wb.y, t0);
        t0 = __builtin_fmaf(xv[6],  wb.z, t0);
        t0 = __builtin_fmaf(xv[7],  wb.w, t0);
        u0 = __builtin_fmaf(xv[4],  wa.x, u0);
        u0 = __builtin_fmaf(xv[5],  wa.y, u0);
        u0 = __builtin_fmaf(xv[6],  wa.z, u0);
        u0 = __builtin_fmaf(xv[7],  wa.w, u0);
        u0 = __builtin_fmaf(xv[8],  wb.x, u0);
        u0 = __builtin_fmaf(xv[9],  wb.y, u0);
        u0 = __builtin_fmaf(xv[10], wb.z, u0);
        u0 = __builtin_fmaf(xv[11], wb.w, u0);

        const float g0 = tgelu(t0, sT);
        const float g1 = tgelu(u0, sT);
        acc0.x = __builtin_fmaf(g0, w2a, acc0.x);
        acc0.y = __builtin_fmaf(g0, w2b, acc0.y);
        acc1.x = __builtin_fmaf(g1, w2a, acc1.x);
        acc1.y = __builtin_fmaf(g1, w2b, acc1.y);
    }

    // out[((b*511 + p)*256 + c)*2 + o] : contiguous float2 per thread, coalesced across c
    float* ob = out + ((size_t)(b * P_CNT) * C_DIM + c) * 2;
    *(float2*)(ob + (size_t)p0 * (C_DIM * 2)) = acc0;           // p0 <= 510 always valid
    if (p0 + 1 < P_CNT)
        *(float2*)(ob + (size_t)(p0 + 1) * (C_DIM * 2)) = acc1;
}

extern "C" void kernel_launch(void* const* d_in, const int* in_sizes, int n_in,
                              void* d_out, int out_size, void* d_ws, size_t ws_size,
                              hipStream_t stream) {
    const float* X  = (const float*)d_in[0];
    const float* W1 = (const float*)d_in[1];
    const float* b1 = (const float*)d_in[2];
    const float* W2 = (const float*)d_in[3];
    const float* b2 = (const float*)d_in[4];
    float* out = (float*)d_out;

    offset_predictor_kernel<<<2048, 256, 0, stream>>>(X, W1, b1, W2, b2, out);
}